// Round 7
// baseline (299.401 us; speedup 1.0000x reference)
//
#include <hip/hip_runtime.h>

typedef unsigned short ushort;
typedef unsigned int uint;
typedef __attribute__((ext_vector_type(8))) short short8;
typedef __attribute__((ext_vector_type(4))) float f32x4;

#define B_    8192
#define D_    128
#define K_    32
#define NV_   50000
#define SC_   28.853900817779268f   /* log2(e)/eps */
#define ISC_  0.03465735902799726f  /* eps*ln2     */

/* ws float offsets */
#define WS_HF    0
#define WS_LHF2  16
#define WS_W1T   32        /* 4096 floats: w1T[u][d] */
#define WS_TBL   4128      /* 2048 floats: [k*16+j]*4 = {cct, cc2, f2, pad} */
#define WS_ALPHA 6176      /* 8192 floats: alpha[b] */
/* ws byte offsets */
#define WSB_FBHI 57472
#define WSB_FBLO 188544
#define WSB_CB1  319616

__device__ __forceinline__ ushort bf16rne(float v) {
    uint u = __float_as_uint(v);
    uint r = (u + 0x7fffu + ((u >> 16) & 1u)) >> 16;
    return (ushort)r;
}
__device__ __forceinline__ float bf16tof(ushort h) { return __uint_as_float(((uint)h) << 16); }

template <int C>
__device__ __forceinline__ float dppmv(float x) {
    return __int_as_float(__builtin_amdgcn_update_dpp(
        __float_as_int(x), __float_as_int(x), C, 0xf, 0xf, false));
}
__device__ __forceinline__ float rowmax16(float x) {
    x = fmaxf(x, dppmv<0x121>(x));
    x = fmaxf(x, dppmv<0x122>(x));
    x = fmaxf(x, dppmv<0x124>(x));
    x = fmaxf(x, dppmv<0x128>(x));
    return x;
}
__device__ __forceinline__ float rowmin16(float x) {
    x = fminf(x, dppmv<0x121>(x));
    x = fminf(x, dppmv<0x122>(x));
    x = fminf(x, dppmv<0x124>(x));
    x = fminf(x, dppmv<0x128>(x));
    return x;
}
__device__ __forceinline__ float rowsum16(float x) {
    x += dppmv<0x121>(x);
    x += dppmv<0x122>(x);
    x += dppmv<0x124>(x);
    x += dppmv<0x128>(x);
    return x;
}
__device__ __forceinline__ f32x4 mfma16(short8 a, short8 b, f32x4 c) {
    return __builtin_amdgcn_mfma_f32_16x16x32_bf16(a, b, c, 0, 0, 0);
}
__device__ __forceinline__ uint cvtpk_bf16(float a, float b) {
    uint r;
    asm("v_cvt_pk_bf16_f32 %0, %1, %2" : "=v"(r) : "v"(a), "v"(b));
    return r;
}

/* ---- init: F fragments (hi/lo split, B-frag order) ---- */
__global__ __launch_bounds__(512) void init_fb(const float* __restrict__ Ff, float* __restrict__ ws) {
    int idx = blockIdx.x * 512 + threadIdx.x;  /* [0, 65536) */
    int e = idx & 7, l = (idx >> 3) & 63, s = (idx >> 9) & 3, k = idx >> 11;
    int j = l & 15, kg = l >> 4;
    int d = s * 32 + kg * 8 + e;
    float v = Ff[(j * D_ + d) * K_ + k];
    ushort hb = bf16rne(v);
    ushort lb = bf16rne(v - bf16tof(hb));
    ushort* FBHI = (ushort*)((char*)ws + WSB_FBHI);
    ushort* FBLO = (ushort*)((char*)ws + WSB_FBLO);
    FBHI[idx] = hb;
    FBLO[idx] = lb;
}

/* ---- init: hf, lhf2, w1T, packed tbl, C fragments ---- */
__global__ __launch_bounds__(1024) void init_small(
    const float* __restrict__ C_up, const float* __restrict__ Ff,
    const float* __restrict__ h_logits, const float* __restrict__ w1,
    float* __restrict__ ws) {
    __shared__ float hf[16];
    __shared__ float Cs[16][16][32];
    __shared__ float f2p[16][32][2];
    const int t = threadIdx.x;

    if (t == 0) {
        float m = -3.4e38f;
        for (int p = 0; p < 16; ++p) m = fmaxf(m, h_logits[p]);
        float e[16], s = 0.f;
        for (int p = 0; p < 16; ++p) { e[p] = __expf(h_logits[p] - m); s += e[p]; }
        for (int p = 0; p < 16; ++p) {
            hf[p] = e[p] / s;
            ws[WS_HF + p] = hf[p];
            ws[WS_LHF2 + p] = log2f(hf[p]);
        }
    }
    for (int e0 = t; e0 < 16 * 16 * 32; e0 += 1024) {
        int k = e0 & 31, j = (e0 >> 5) & 15, q = e0 >> 9;
        float v = 0.f;
        if (q < j)      { int pi = q * (31 - q) / 2 + (j - q - 1); v = fmaxf(C_up[pi * 32 + k], 0.f); }
        else if (j < q) { int pi = j * (31 - j) / 2 + (q - j - 1); v = fmaxf(C_up[pi * 32 + k], 0.f); }
        Cs[q][j][k] = v;
    }
    for (int e0 = t; e0 < 4096; e0 += 1024) {
        int u = e0 >> 7, d = e0 & 127;
        ws[WS_W1T + e0] = w1[d * 32 + u];
    }
    {
        int k = t & 31, half = (t >> 5) & 1, j = t >> 6;
        float s = 0.f;
        for (int dd = 0; dd < 64; ++dd) {
            int d = half * 64 + dd;
            float f = Ff[(j * D_ + d) * K_ + k];
            s += f * f;
        }
        f2p[j][k][half] = s;
    }
    __syncthreads();

    if (t < 512) {
        int k = t >> 4, j = t & 15;
        float s1 = 0.f, s2 = 0.f;
        for (int q = 0; q < 16; ++q) {
            float c = Cs[q][j][k];
            s1 += hf[q] * c;
            s2 += hf[q] * c * c;
        }
        ws[WS_TBL + t * 4 + 0] = s1;
        ws[WS_TBL + t * 4 + 1] = s2;
        ws[WS_TBL + t * 4 + 3] = 0.f;
    } else {
        int t2 = t - 512;               /* [0,512): j = t2>>5, k = t2&31 */
        int j = t2 >> 5, k = t2 & 31;
        ws[WS_TBL + (k * 16 + j) * 4 + 2] = f2p[j][k][0] + f2p[j][k][1];
    }
    {
        ushort* CB1 = (ushort*)((char*)ws + WSB_CB1);
        for (int i0 = t; i0 < 16384; i0 += 1024) {
            int e = i0 & 7, l = (i0 >> 3) & 63, k = i0 >> 9;
            int kg = l >> 4, j = l & 15, q = (kg & 1) * 8 + e;
            CB1[i0] = (kg < 2) ? bf16rne(Cs[q][j][k]) : (ushort)0;
        }
    }
}

/* ---- alpha pre-kernel: one wave per graph ---- */
__global__ __launch_bounds__(64) void alpha_k(
    const float* __restrict__ features, const int* __restrict__ idxs,
    const float* __restrict__ b1, const float* __restrict__ w2,
    const float* __restrict__ b2, float* __restrict__ ws) {
    __shared__ float pooled_s[128];
    __shared__ int idl[16];
    const int b = blockIdx.x, l = threadIdx.x;
    if (l < 16) idl[l] = idxs[b * 16 + l];
    __syncthreads();
    float p0 = 0.f, p1 = 0.f;
    #pragma unroll 4
    for (int i = 0; i < 16; ++i) {
        int ix = idl[i];
        if (ix < NV_) {
            p0 += features[(size_t)ix * D_ + l];
            p1 += features[(size_t)ix * D_ + 64 + l];
        }
    }
    pooled_s[l] = p0 * (1.f / 16.f);
    pooled_s[64 + l] = p1 * (1.f / 16.f);
    __syncthreads();
    float z = 0.f;
    if (l < 32) {
        float h = b1[l];
        const float4* wrow = (const float4*)(ws + WS_W1T + l * 128);
        #pragma unroll 4
        for (int dd = 0; dd < 32; ++dd) {
            float4 w4 = wrow[dd];
            h = fmaf(pooled_s[dd * 4 + 0], w4.x, h);
            h = fmaf(pooled_s[dd * 4 + 1], w4.y, h);
            h = fmaf(pooled_s[dd * 4 + 2], w4.z, h);
            h = fmaf(pooled_s[dd * 4 + 3], w4.w, h);
        }
        h = fmaxf(h, 0.f);
        z = h * w2[l];
    }
    #pragma unroll
    for (int s = 1; s < 64; s <<= 1) z += __shfl_xor(z, s);
    if (l == 0) ws[WS_ALPHA + b] = 1.f / (1.f + __expf(-(z + b2[0])));
}

/* ---- main: 256-thread block, one graph, 8 k per wave ---- */
__global__ __launch_bounds__(256, 6) void fgw_main(
    const float* __restrict__ adj, const float* __restrict__ features,
    const int* __restrict__ idxs,
    const float* __restrict__ ws, float* __restrict__ out) {
    __shared__ __align__(16) ushort xA[2][4][64][8];   /* 8 KB */
    __shared__ __align__(16) uint  exchbuf[1536];      /* 6 KB: 4 waves x 384 */
    __shared__ __align__(16) ushort adjA[64][8];       /* 1 KB */
    __shared__ float adj_s[16][17];
    __shared__ float x2part[16][8];
    __shared__ __align__(16) float x2s[16];
    __shared__ __align__(16) float c1s[16];
    __shared__ __align__(16) float rss[16];            /* pre-scaled by 1/16 */
    __shared__ int idx_sh[16];

    const int t = threadIdx.x;
    const int blk = blockIdx.x;

    adj_s[(t >> 4) & 15][t & 15] = adj[blk * 256 + t];
    if (t < 16) idx_sh[t] = idxs[blk * 16 + t];
    __syncthreads();

    if (t < 128) {
        int i = t >> 3, c = t & 7;
        int ix = idx_sh[i];
        float vv[16];
        if (ix < NV_) {
            const float4* fp = (const float4*)(features + (size_t)ix * D_ + c * 16);
            float4 q0 = fp[0], q1 = fp[1], q2 = fp[2], q3 = fp[3];
            vv[0] = q0.x; vv[1] = q0.y; vv[2] = q0.z; vv[3] = q0.w;
            vv[4] = q1.x; vv[5] = q1.y; vv[6] = q1.z; vv[7] = q1.w;
            vv[8] = q2.x; vv[9] = q2.y; vv[10] = q2.z; vv[11] = q2.w;
            vv[12] = q3.x; vv[13] = q3.y; vv[14] = q3.z; vv[15] = q3.w;
        } else {
            #pragma unroll
            for (int e = 0; e < 16; ++e) vv[e] = 0.f;
        }
        float s2 = 0.f;
        #pragma unroll
        for (int e = 0; e < 16; ++e) s2 += vv[e] * vv[e];
        x2part[i][c] = s2;
        #pragma unroll
        for (int g = 0; g < 2; ++g) {
            int d0 = c * 16 + g * 8;
            int s = d0 >> 5, kg = (d0 >> 3) & 3;
            union { short8 v; ushort u[8]; } h8, l8;
            #pragma unroll
            for (int e = 0; e < 8; ++e) {
                float x = vv[g * 8 + e];
                ushort hb = bf16rne(x);
                h8.u[e] = hb;
                l8.u[e] = bf16rne(x - bf16tof(hb));
            }
            *(short8*)&xA[0][s][kg * 16 + i][0] = h8.v;
            *(short8*)&xA[1][s][kg * 16 + i][0] = l8.v;
        }
    } else if (t < 192) {
        int l = t - 128;
        int i = l & 15, kg = l >> 4;
        union { short8 v; ushort u[8]; } f8;
        #pragma unroll
        for (int e = 0; e < 8; ++e) {
            int p = (kg & 1) * 8 + e;
            float v = adj_s[i][p];
            ushort hb = bf16rne(v);
            f8.u[e] = (kg < 2) ? hb : bf16rne(v - bf16tof(hb));
        }
        *(short8*)&adjA[l][0] = f8.v;
    } else if (t < 208) {
        int i = t - 192;
        float s = 0.f, s2 = 0.f;
        for (int p = 0; p < 16; ++p) { float a = adj_s[i][p]; s += a; s2 += a * a; }
        rss[i] = s * (1.f / 16.f);
        c1s[i] = s2 * (1.f / 16.f);
    }
    __syncthreads();
    if (t < 16) {
        float s = 0.f;
        #pragma unroll
        for (int c = 0; c < 8; ++c) s += x2part[t][c];
        x2s[t] = s;
    }
    __syncthreads();

    const int w = t >> 6, l = t & 63;
    const int jl = l & 15, ig = l >> 4;

    /* hoisted per-lane state */
    const float alpha = ws[WS_ALPHA + blk];
    const float oma = 1.f - alpha;
    const float soma = SC_ * oma, salpha = SC_ * alpha, ta2 = 2.f * alpha;
    const float n2soma = -2.f * soma;
    const float lq2 = ws[WS_LHF2 + jl];
    const float hfj = ws[WS_HF + jl];
    const short8 Aadj = *(const short8*)&adjA[l][0];
    const f32x4 x2v = *(const f32x4*)&x2s[ig * 4];
    const f32x4 c1v = *(const f32x4*)&c1s[ig * 4];
    const f32x4 rsv = *(const f32x4*)&rss[ig * 4];
    float A1[4], mB1[4], TB1[4];
    #pragma unroll
    for (int r = 0; r < 4; ++r) {
        A1[r]  = fmaf(soma, x2v[r], salpha * c1v[r]);
        mB1[r] = -2.f * salpha * rsv[r];
        TB1[r] = ta2 * rsv[r];
    }

    const char* pH = (const char*)ws + WSB_FBHI + (w * 4) * 1024 + l * 16;
    const char* pL = (const char*)ws + WSB_FBLO + (w * 4) * 1024 + l * 16;
    const char* pC = (const char*)ws + WSB_CB1 + w * 1024 + l * 16;
    const float* pT = ws + WS_TBL + (w * 16 + jl) * 4;
    uint* Tb = exchbuf + w * 384;         /* 16 x 12 uints */
    ushort* Mbs = (ushort*)(Tb + 192);    /* 16 x 24 ushorts */

    #pragma unroll 1
    for (int kk = 0; kk < 8; ++kk) {
        f32x4 acc = {0.f, 0.f, 0.f, 0.f};
        #pragma unroll
        for (int s = 0; s < 4; ++s) {
            const short8 Bh = *(const short8*)(pH + s * 1024);
            const short8 Bl = *(const short8*)(pL + s * 1024);
            const short8 Ah = *(const short8*)&xA[0][s][l][0];
            const short8 Al = *(const short8*)&xA[1][s][l][0];
            acc = mfma16(Ah, Bh, acc);
            acc = mfma16(Al, Bh, acc);
            acc = mfma16(Ah, Bl, acc);
        }
        pH += 16384; pL += 16384;
        const short8 C1f = *(const short8*)pC; pC += 4096;
        const float4 tb = *(const float4*)pT; pT += 256;
        const float cctv = tb.x, cc2v = tb.y, f2v = tb.z;

        const float c0 = fmaf(soma, f2v, salpha * cc2v);
        float Chat[4];
        #pragma unroll
        for (int r = 0; r < 4; ++r)
            Chat[r] = fmaf(n2soma, acc[r], fmaf(mB1[r], cctv, A1[r] + c0));

        /* sinkhorn iter 1 row (G=0): use rowmin */
        float Fh[4];
        #pragma unroll
        for (int r = 0; r < 4; ++r) {
            float mn = rowmin16(Chat[r]);
            float e = exp2f(mn - Chat[r]);
            float S = rowsum16(e);
            Fh[r] = (mn - 4.f) - log2f(S);
        }
        /* col 1 */
        float diff[4];
        #pragma unroll
        for (int r = 0; r < 4; ++r) diff[r] = Fh[r] - Chat[r];
        float m2 = fmaxf(fmaxf(fmaxf(diff[0], diff[1]), diff[2]), diff[3]);
        m2 = fmaxf(m2, __shfl_xor(m2, 16));
        m2 = fmaxf(m2, __shfl_xor(m2, 32));
        float S2 = 0.f;
        #pragma unroll
        for (int r = 0; r < 4; ++r) S2 += exp2f(diff[r] - m2);
        S2 += __shfl_xor(S2, 16);
        S2 += __shfl_xor(S2, 32);
        float G = lq2 - m2 - log2f(S2);
        /* iter 2 row */
        #pragma unroll
        for (int r = 0; r < 4; ++r) {
            float a = G - Chat[r];
            float m = rowmax16(a);
            float e = exp2f(a - m);
            float S = rowsum16(e);
            Fh[r] = (-4.f - m) - log2f(S);
        }
        /* col 2 (final): Tv = e2 * hf / S2, no log2/G needed */
        #pragma unroll
        for (int r = 0; r < 4; ++r) diff[r] = Fh[r] - Chat[r];
        m2 = fmaxf(fmaxf(fmaxf(diff[0], diff[1]), diff[2]), diff[3]);
        m2 = fmaxf(m2, __shfl_xor(m2, 16));
        m2 = fmaxf(m2, __shfl_xor(m2, 32));
        float e2[4];
        S2 = 0.f;
        #pragma unroll
        for (int r = 0; r < 4; ++r) { e2[r] = exp2f(diff[r] - m2); S2 += e2[r]; }
        S2 += __shfl_xor(S2, 16);
        S2 += __shfl_xor(S2, 32);
        const float wgt = hfj * __builtin_amdgcn_rcpf(S2);
        float Tv[4];
        #pragma unroll
        for (int r = 0; r < 4; ++r) Tv[r] = e2[r] * wgt;

        /* T exchange (packed bf16) -> tmp = adj @ T (hi+lo in one MFMA) */
        Tb[jl * 12 + ig * 2]     = cvtpk_bf16(Tv[0], Tv[1]);
        Tb[jl * 12 + ig * 2 + 1] = cvtpk_bf16(Tv[2], Tv[3]);
        const short8 Bt = *(const short8*)&Tb[jl * 12 + (ig & 1) * 4];
        f32x4 tmpv = mfma16(Aadj, Bt, (f32x4){0.f, 0.f, 0.f, 0.f});

        /* tmp exchange (bf16 row-major [16][24]) -> cross = tmp @ C_k */
        #pragma unroll
        for (int r = 0; r < 4; ++r)
            Mbs[(ig * 4 + r) * 24 + jl] = (ushort)cvtpk_bf16(tmpv[r], tmpv[r]);
        const short8 Atm = *(const short8*)&Mbs[jl * 24 + (ig & 1) * 8];
        f32x4 cr = mfma16(Atm, C1f, (f32x4){0.f, 0.f, 0.f, 0.f});

        float dot = 0.f;
        #pragma unroll
        for (int r = 0; r < 4; ++r) {
            float fc = fmaf(ISC_, Chat[r], fmaf(TB1[r], cctv, -ta2 * cr[r]));
            dot = fmaf(Tv[r], fc, dot);
        }
        dot = rowsum16(dot);
        dot += __shfl_xor(dot, 16);
        dot += __shfl_xor(dot, 32);
        if (l == 0) out[blk * K_ + kk * 4 + w] = dot;
    }
}

extern "C" void kernel_launch(void* const* d_in, const int* in_sizes, int n_in,
                              void* d_out, int out_size, void* d_ws, size_t ws_size,
                              hipStream_t stream) {
    (void)in_sizes; (void)n_in; (void)out_size; (void)ws_size;
    const float* adj      = (const float*)d_in[0];
    const float* features = (const float*)d_in[1];
    const int*   idxs     = (const int*)  d_in[2];
    const float* C_up     = (const float*)d_in[3];
    const float* Ff       = (const float*)d_in[4];
    const float* h_logits = (const float*)d_in[5];
    const float* w1       = (const float*)d_in[6];
    const float* b1       = (const float*)d_in[7];
    const float* w2       = (const float*)d_in[8];
    const float* b2       = (const float*)d_in[9];
    float* out = (float*)d_out;
    float* ws  = (float*)d_ws;

    hipLaunchKernelGGL(init_fb, dim3(128), dim3(512), 0, stream, Ff, ws);
    hipLaunchKernelGGL(init_small, dim3(1), dim3(1024), 0, stream, C_up, Ff, h_logits, w1, ws);
    hipLaunchKernelGGL(alpha_k, dim3(B_), dim3(64), 0, stream, features, idxs, b1, w2, b2, ws);
    hipLaunchKernelGGL(fgw_main, dim3(B_), dim3(256), 0, stream,
                       adj, features, idxs, ws, out);
}

// Round 13
// 295.742 us; speedup vs baseline: 1.0124x; 1.0124x over previous
//
#include <hip/hip_runtime.h>

typedef unsigned short ushort;
typedef unsigned int uint;
typedef __attribute__((ext_vector_type(8))) short short8;
typedef __attribute__((ext_vector_type(4))) float f32x4;

#define B_    8192
#define D_    128
#define K_    32
#define NV_   50000
#define SC_   28.853900817779268f   /* log2(e)/eps */
#define ISC_  0.03465735902799726f  /* eps*ln2     */

/* ws float offsets */
#define WS_HF    0
#define WS_LHF2  16
#define WS_W1T   32        /* 4096 floats: w1T[u][d] */
#define WS_TBL   4128      /* 2048 floats: [k*16+j]*4 = {cct, cc2, f2, pad} */
#define WS_ALPHA 6176      /* 8192 floats: alpha[b] */
/* ws byte offsets */
#define WSB_FBHI 57472
#define WSB_FBLO 188544
#define WSB_CB1  319616

__device__ __forceinline__ ushort bf16rne(float v) {
    uint u = __float_as_uint(v);
    uint r = (u + 0x7fffu + ((u >> 16) & 1u)) >> 16;
    return (ushort)r;
}
__device__ __forceinline__ float bf16tof(ushort h) { return __uint_as_float(((uint)h) << 16); }

template <int C>
__device__ __forceinline__ float dppmv(float x) {
    return __int_as_float(__builtin_amdgcn_update_dpp(
        __float_as_int(x), __float_as_int(x), C, 0xf, 0xf, false));
}
__device__ __forceinline__ float rowmax16(float x) {
    x = fmaxf(x, dppmv<0x121>(x));
    x = fmaxf(x, dppmv<0x122>(x));
    x = fmaxf(x, dppmv<0x124>(x));
    x = fmaxf(x, dppmv<0x128>(x));
    return x;
}
__device__ __forceinline__ float rowmin16(float x) {
    x = fminf(x, dppmv<0x121>(x));
    x = fminf(x, dppmv<0x122>(x));
    x = fminf(x, dppmv<0x124>(x));
    x = fminf(x, dppmv<0x128>(x));
    return x;
}
__device__ __forceinline__ float rowsum16(float x) {
    x += dppmv<0x121>(x);
    x += dppmv<0x122>(x);
    x += dppmv<0x124>(x);
    x += dppmv<0x128>(x);
    return x;
}
__device__ __forceinline__ f32x4 mfma16(short8 a, short8 b, f32x4 c) {
    return __builtin_amdgcn_mfma_f32_16x16x32_bf16(a, b, c, 0, 0, 0);
}
__device__ __forceinline__ uint cvtpk_bf16(float a, float b) {
    uint r;
    asm("v_cvt_pk_bf16_f32 %0, %1, %2" : "=v"(r) : "v"(a), "v"(b));
    return r;
}

/* ---- init: F fragments (hi/lo split, B-frag order) ---- */
__global__ __launch_bounds__(512) void init_fb(const float* __restrict__ Ff, float* __restrict__ ws) {
    int idx = blockIdx.x * 512 + threadIdx.x;  /* [0, 65536) */
    int e = idx & 7, l = (idx >> 3) & 63, s = (idx >> 9) & 3, k = idx >> 11;
    int j = l & 15, kg = l >> 4;
    int d = s * 32 + kg * 8 + e;
    float v = Ff[(j * D_ + d) * K_ + k];
    ushort hb = bf16rne(v);
    ushort lb = bf16rne(v - bf16tof(hb));
    ushort* FBHI = (ushort*)((char*)ws + WSB_FBHI);
    ushort* FBLO = (ushort*)((char*)ws + WSB_FBLO);
    FBHI[idx] = hb;
    FBLO[idx] = lb;
}

/* ---- init: hf, lhf2, w1T, packed tbl, C fragments ---- */
__global__ __launch_bounds__(1024) void init_small(
    const float* __restrict__ C_up, const float* __restrict__ Ff,
    const float* __restrict__ h_logits, const float* __restrict__ w1,
    float* __restrict__ ws) {
    __shared__ float hf[16];
    __shared__ float Cs[16][16][32];
    __shared__ float f2p[16][32][2];
    const int t = threadIdx.x;

    if (t == 0) {
        float m = -3.4e38f;
        for (int p = 0; p < 16; ++p) m = fmaxf(m, h_logits[p]);
        float e[16], s = 0.f;
        for (int p = 0; p < 16; ++p) { e[p] = __expf(h_logits[p] - m); s += e[p]; }
        for (int p = 0; p < 16; ++p) {
            hf[p] = e[p] / s;
            ws[WS_HF + p] = hf[p];
            ws[WS_LHF2 + p] = log2f(hf[p]);
        }
    }
    for (int e0 = t; e0 < 16 * 16 * 32; e0 += 1024) {
        int k = e0 & 31, j = (e0 >> 5) & 15, q = e0 >> 9;
        float v = 0.f;
        if (q < j)      { int pi = q * (31 - q) / 2 + (j - q - 1); v = fmaxf(C_up[pi * 32 + k], 0.f); }
        else if (j < q) { int pi = j * (31 - j) / 2 + (q - j - 1); v = fmaxf(C_up[pi * 32 + k], 0.f); }
        Cs[q][j][k] = v;
    }
    for (int e0 = t; e0 < 4096; e0 += 1024) {
        int u = e0 >> 7, d = e0 & 127;
        ws[WS_W1T + e0] = w1[d * 32 + u];
    }
    {
        int k = t & 31, half = (t >> 5) & 1, j = t >> 6;
        float s = 0.f;
        for (int dd = 0; dd < 64; ++dd) {
            int d = half * 64 + dd;
            float f = Ff[(j * D_ + d) * K_ + k];
            s += f * f;
        }
        f2p[j][k][half] = s;
    }
    __syncthreads();

    if (t < 512) {
        int k = t >> 4, j = t & 15;
        float s1 = 0.f, s2 = 0.f;
        for (int q = 0; q < 16; ++q) {
            float c = Cs[q][j][k];
            s1 += hf[q] * c;
            s2 += hf[q] * c * c;
        }
        ws[WS_TBL + t * 4 + 0] = s1;
        ws[WS_TBL + t * 4 + 1] = s2;
        ws[WS_TBL + t * 4 + 3] = 0.f;
    } else {
        int t2 = t - 512;               /* [0,512): j = t2>>5, k = t2&31 */
        int j = t2 >> 5, k = t2 & 31;
        ws[WS_TBL + (k * 16 + j) * 4 + 2] = f2p[j][k][0] + f2p[j][k][1];
    }
    {
        ushort* CB1 = (ushort*)((char*)ws + WSB_CB1);
        for (int i0 = t; i0 < 16384; i0 += 1024) {
            int e = i0 & 7, l = (i0 >> 3) & 63, k = i0 >> 9;
            int kg = l >> 4, j = l & 15, q = (kg & 1) * 8 + e;
            CB1[i0] = (kg < 2) ? bf16rne(Cs[q][j][k]) : (ushort)0;
        }
    }
}

/* ---- alpha pre-kernel: one wave per graph ---- */
__global__ __launch_bounds__(64) void alpha_k(
    const float* __restrict__ features, const int* __restrict__ idxs,
    const float* __restrict__ b1, const float* __restrict__ w2,
    const float* __restrict__ b2, float* __restrict__ ws) {
    __shared__ float pooled_s[128];
    __shared__ int idl[16];
    const int b = blockIdx.x, l = threadIdx.x;
    if (l < 16) idl[l] = idxs[b * 16 + l];
    __syncthreads();
    float p0 = 0.f, p1 = 0.f;
    #pragma unroll 4
    for (int i = 0; i < 16; ++i) {
        int ix = idl[i];
        if (ix < NV_) {
            p0 += features[(size_t)ix * D_ + l];
            p1 += features[(size_t)ix * D_ + 64 + l];
        }
    }
    pooled_s[l] = p0 * (1.f / 16.f);
    pooled_s[64 + l] = p1 * (1.f / 16.f);
    __syncthreads();
    float z = 0.f;
    if (l < 32) {
        float h = b1[l];
        const float4* wrow = (const float4*)(ws + WS_W1T + l * 128);
        #pragma unroll 4
        for (int dd = 0; dd < 32; ++dd) {
            float4 w4 = wrow[dd];
            h = fmaf(pooled_s[dd * 4 + 0], w4.x, h);
            h = fmaf(pooled_s[dd * 4 + 1], w4.y, h);
            h = fmaf(pooled_s[dd * 4 + 2], w4.z, h);
            h = fmaf(pooled_s[dd * 4 + 3], w4.w, h);
        }
        h = fmaxf(h, 0.f);
        z = h * w2[l];
    }
    #pragma unroll
    for (int s = 1; s < 64; s <<= 1) z += __shfl_xor(z, s);
    if (l == 0) ws[WS_ALPHA + b] = 1.f / (1.f + __expf(-(z + b2[0])));
}

/* ---- main: 256-thread block, one graph, 8 k per wave ---- */
__global__ __launch_bounds__(256, 6) void fgw_main(
    const float* __restrict__ adj, const float* __restrict__ features,
    const int* __restrict__ idxs,
    const float* __restrict__ ws, float* __restrict__ out) {
    __shared__ __align__(16) ushort xA[2][4][64][8];   /* 8 KB */
    __shared__ __align__(16) uint  exchbuf[1536];      /* 6 KB: 4 waves x 384 */
    __shared__ __align__(16) ushort adjA[64][8];       /* 1 KB */
    __shared__ float adj_s[16][17];
    __shared__ float x2part[16][8];
    __shared__ __align__(16) float x2s[16];
    __shared__ __align__(16) float c1s[16];
    __shared__ __align__(16) float rss[16];            /* pre-scaled by 1/16 */
    __shared__ int idx_sh[16];

    const int t = threadIdx.x;
    const int blk = blockIdx.x;

    adj_s[(t >> 4) & 15][t & 15] = adj[blk * 256 + t];
    if (t < 16) idx_sh[t] = idxs[blk * 16 + t];
    __syncthreads();

    if (t < 128) {
        int i = t >> 3, c = t & 7;
        int ix = idx_sh[i];
        float vv[16];
        if (ix < NV_) {
            const float4* fp = (const float4*)(features + (size_t)ix * D_ + c * 16);
            float4 q0 = fp[0], q1 = fp[1], q2 = fp[2], q3 = fp[3];
            vv[0] = q0.x; vv[1] = q0.y; vv[2] = q0.z; vv[3] = q0.w;
            vv[4] = q1.x; vv[5] = q1.y; vv[6] = q1.z; vv[7] = q1.w;
            vv[8] = q2.x; vv[9] = q2.y; vv[10] = q2.z; vv[11] = q2.w;
            vv[12] = q3.x; vv[13] = q3.y; vv[14] = q3.z; vv[15] = q3.w;
        } else {
            #pragma unroll
            for (int e = 0; e < 16; ++e) vv[e] = 0.f;
        }
        float s2 = 0.f;
        #pragma unroll
        for (int e = 0; e < 16; ++e) s2 += vv[e] * vv[e];
        x2part[i][c] = s2;
        #pragma unroll
        for (int g = 0; g < 2; ++g) {
            int d0 = c * 16 + g * 8;
            int s = d0 >> 5, kg = (d0 >> 3) & 3;
            union { short8 v; ushort u[8]; } h8, l8;
            #pragma unroll
            for (int e = 0; e < 8; ++e) {
                float x = vv[g * 8 + e];
                ushort hb = bf16rne(x);
                h8.u[e] = hb;
                l8.u[e] = bf16rne(x - bf16tof(hb));
            }
            *(short8*)&xA[0][s][kg * 16 + i][0] = h8.v;
            *(short8*)&xA[1][s][kg * 16 + i][0] = l8.v;
        }
    } else if (t < 192) {
        int l = t - 128;
        int i = l & 15, kg = l >> 4;
        union { short8 v; ushort u[8]; } f8;
        #pragma unroll
        for (int e = 0; e < 8; ++e) {
            int p = (kg & 1) * 8 + e;
            float v = adj_s[i][p];
            ushort hb = bf16rne(v);
            f8.u[e] = (kg < 2) ? hb : bf16rne(v - bf16tof(hb));
        }
        *(short8*)&adjA[l][0] = f8.v;
    } else if (t < 208) {
        int i = t - 192;
        float s = 0.f, s2 = 0.f;
        for (int p = 0; p < 16; ++p) { float a = adj_s[i][p]; s += a; s2 += a * a; }
        rss[i] = s * (1.f / 16.f);
        c1s[i] = s2 * (1.f / 16.f);
    }
    __syncthreads();
    if (t < 16) {
        float s = 0.f;
        #pragma unroll
        for (int c = 0; c < 8; ++c) s += x2part[t][c];
        x2s[t] = s;
    }
    __syncthreads();

    const int w = t >> 6, l = t & 63;
    const int jl = l & 15, ig = l >> 4;

    /* hoisted per-lane state */
    const float alpha = ws[WS_ALPHA + blk];
    const float oma = 1.f - alpha;
    const float soma = SC_ * oma, salpha = SC_ * alpha, ta2 = 2.f * alpha;
    const float n2soma = -2.f * soma;
    const float lq2 = ws[WS_LHF2 + jl];
    const float hfj = ws[WS_HF + jl];
    const short8 Aadj = *(const short8*)&adjA[l][0];
    const f32x4 x2v = *(const f32x4*)&x2s[ig * 4];
    const f32x4 c1v = *(const f32x4*)&c1s[ig * 4];
    const f32x4 rsv = *(const f32x4*)&rss[ig * 4];
    float A1[4], mB1[4], TB1[4];
    #pragma unroll
    for (int r = 0; r < 4; ++r) {
        A1[r]  = fmaf(soma, x2v[r], salpha * c1v[r]);
        mB1[r] = -2.f * salpha * rsv[r];
        TB1[r] = ta2 * rsv[r];
    }

    const char* pH = (const char*)ws + WSB_FBHI + (w * 4) * 1024 + l * 16;
    const char* pL = (const char*)ws + WSB_FBLO + (w * 4) * 1024 + l * 16;
    const char* pC = (const char*)ws + WSB_CB1 + w * 1024 + l * 16;
    const float* pT = ws + WS_TBL + (w * 16 + jl) * 4;
    uint* Tb = exchbuf + w * 384;         /* 16 x 12 uints */
    ushort* Mbs = (ushort*)(Tb + 192);    /* 16 x 24 ushorts */

    #pragma unroll 1
    for (int kk = 0; kk < 8; ++kk) {
        f32x4 acc = {0.f, 0.f, 0.f, 0.f};
        #pragma unroll
        for (int s = 0; s < 4; ++s) {
            const short8 Bh = *(const short8*)(pH + s * 1024);
            const short8 Bl = *(const short8*)(pL + s * 1024);
            const short8 Ah = *(const short8*)&xA[0][s][l][0];
            const short8 Al = *(const short8*)&xA[1][s][l][0];
            acc = mfma16(Ah, Bh, acc);
            acc = mfma16(Al, Bh, acc);
            acc = mfma16(Ah, Bl, acc);
        }
        pH += 16384; pL += 16384;
        const short8 C1f = *(const short8*)pC; pC += 4096;
        const float4 tb = *(const float4*)pT; pT += 256;
        const float cctv = tb.x, cc2v = tb.y, f2v = tb.z;

        const float c0 = fmaf(soma, f2v, salpha * cc2v);
        float Chat[4];
        #pragma unroll
        for (int r = 0; r < 4; ++r)
            Chat[r] = fmaf(n2soma, acc[r], fmaf(mB1[r], cctv, A1[r] + c0));

        /* sinkhorn iter 1 row (G=0): use rowmin */
        float Fh[4];
        #pragma unroll
        for (int r = 0; r < 4; ++r) {
            float mn = rowmin16(Chat[r]);
            float e = exp2f(mn - Chat[r]);
            float S = rowsum16(e);
            Fh[r] = (mn - 4.f) - log2f(S);
        }
        /* col 1 */
        float diff[4];
        #pragma unroll
        for (int r = 0; r < 4; ++r) diff[r] = Fh[r] - Chat[r];
        float m2 = fmaxf(fmaxf(fmaxf(diff[0], diff[1]), diff[2]), diff[3]);
        m2 = fmaxf(m2, __shfl_xor(m2, 16));
        m2 = fmaxf(m2, __shfl_xor(m2, 32));
        float S2 = 0.f;
        #pragma unroll
        for (int r = 0; r < 4; ++r) S2 += exp2f(diff[r] - m2);
        S2 += __shfl_xor(S2, 16);
        S2 += __shfl_xor(S2, 32);
        float G = lq2 - m2 - log2f(S2);
        /* iter 2 row */
        #pragma unroll
        for (int r = 0; r < 4; ++r) {
            float a = G - Chat[r];
            float m = rowmax16(a);
            float e = exp2f(a - m);
            float S = rowsum16(e);
            Fh[r] = (-4.f - m) - log2f(S);
        }
        /* col 2 (final): Tv = e2 * hf / S2, no log2/G needed */
        #pragma unroll
        for (int r = 0; r < 4; ++r) diff[r] = Fh[r] - Chat[r];
        m2 = fmaxf(fmaxf(fmaxf(diff[0], diff[1]), diff[2]), diff[3]);
        m2 = fmaxf(m2, __shfl_xor(m2, 16));
        m2 = fmaxf(m2, __shfl_xor(m2, 32));
        float e2[4];
        S2 = 0.f;
        #pragma unroll
        for (int r = 0; r < 4; ++r) { e2[r] = exp2f(diff[r] - m2); S2 += e2[r]; }
        S2 += __shfl_xor(S2, 16);
        S2 += __shfl_xor(S2, 32);
        const float wgt = hfj * __builtin_amdgcn_rcpf(S2);
        float Tv[4];
        #pragma unroll
        for (int r = 0; r < 4; ++r) Tv[r] = e2[r] * wgt;

        /* T exchange (packed bf16) -> tmp = adj @ T (hi+lo in one MFMA) */
        Tb[jl * 12 + ig * 2]     = cvtpk_bf16(Tv[0], Tv[1]);
        Tb[jl * 12 + ig * 2 + 1] = cvtpk_bf16(Tv[2], Tv[3]);
        const short8 Bt = *(const short8*)&Tb[jl * 12 + (ig & 1) * 4];
        f32x4 tmpv = mfma16(Aadj, Bt, (f32x4){0.f, 0.f, 0.f, 0.f});

        /* tmp exchange (bf16 row-major [16][24]) -> cross = tmp @ C_k */
        #pragma unroll
        for (int r = 0; r < 4; ++r)
            Mbs[(ig * 4 + r) * 24 + jl] = (ushort)cvtpk_bf16(tmpv[r], tmpv[r]);
        const short8 Atm = *(const short8*)&Mbs[jl * 24 + (ig & 1) * 8];
        f32x4 cr = mfma16(Atm, C1f, (f32x4){0.f, 0.f, 0.f, 0.f});

        float dot = 0.f;
        #pragma unroll
        for (int r = 0; r < 4; ++r) {
            float fc = fmaf(ISC_, Chat[r], fmaf(TB1[r], cctv, -ta2 * cr[r]));
            dot = fmaf(Tv[r], fc, dot);
        }
        dot = rowsum16(dot);
        dot += __shfl_xor(dot, 16);
        dot += __shfl_xor(dot, 32);
        if (l == 0) out[blk * K_ + kk * 4 + w] = dot;
    }
}

extern "C" void kernel_launch(void* const* d_in, const int* in_sizes, int n_in,
                              void* d_out, int out_size, void* d_ws, size_t ws_size,
                              hipStream_t stream) {
    (void)in_sizes; (void)n_in; (void)out_size; (void)ws_size;
    const float* adj      = (const float*)d_in[0];
    const float* features = (const float*)d_in[1];
    const int*   idxs     = (const int*)  d_in[2];
    const float* C_up     = (const float*)d_in[3];
    const float* Ff       = (const float*)d_in[4];
    const float* h_logits = (const float*)d_in[5];
    const float* w1       = (const float*)d_in[6];
    const float* b1       = (const float*)d_in[7];
    const float* w2       = (const float*)d_in[8];
    const float* b2       = (const float*)d_in[9];
    float* out = (float*)d_out;
    float* ws  = (float*)d_ws;

    hipLaunchKernelGGL(init_fb, dim3(128), dim3(512), 0, stream, Ff, ws);
    hipLaunchKernelGGL(init_small, dim3(1), dim3(1024), 0, stream, C_up, Ff, h_logits, w1, ws);
    hipLaunchKernelGGL(alpha_k, dim3(B_), dim3(64), 0, stream, features, idxs, b1, w2, b2, ws);
    hipLaunchKernelGGL(fgw_main, dim3(B_), dim3(256), 0, stream,
                       adj, features, idxs, ws, out);
}